// Round 6
// baseline (1172.948 us; speedup 1.0000x reference)
//
#include <hip/hip_runtime.h>
#include <hip/hip_fp16.h>
#include <math.h>

#define DD 128
#define LEAKY 0.5f
#define RPB 32              // rows per bucket (LDS acc = 32*128*4 = 16 KB)
#define MAXBIN 3200         // >= ceil(N/RPB)
#define CHUNK 8192          // edges per partition block
#define MAXBLK 256          // >= ceil(E/CHUNK)
#define PACK_SHIFT 20       // col in low 20 bits, row_local above

// ---------------- gate: fp16, 8 floats -> 8 halves per iter ----------------

__global__ void gate_h_kernel(const float4* __restrict__ emb,
                              const float4* __restrict__ zs,
                              float4* __restrict__ gated_h, int n8) {
    int i = blockIdx.x * blockDim.x + threadIdx.x;
    int stride = gridDim.x * blockDim.x;
    for (; i < n8; i += stride) {
        float4 e0 = emb[2 * i], e1 = emb[2 * i + 1];
        float4 z0 = zs[2 * i], z1 = zs[2 * i + 1];
        float g0 = e0.x * (2.f / (1.f + __expf(-z0.x)) - 1.f);
        float g1 = e0.y * (2.f / (1.f + __expf(-z0.y)) - 1.f);
        float g2 = e0.z * (2.f / (1.f + __expf(-z0.z)) - 1.f);
        float g3 = e0.w * (2.f / (1.f + __expf(-z0.w)) - 1.f);
        float g4 = e1.x * (2.f / (1.f + __expf(-z1.x)) - 1.f);
        float g5 = e1.y * (2.f / (1.f + __expf(-z1.y)) - 1.f);
        float g6 = e1.z * (2.f / (1.f + __expf(-z1.z)) - 1.f);
        float g7 = e1.w * (2.f / (1.f + __expf(-z1.w)) - 1.f);
        union { __half2 h[4]; float4 f; } u;
        u.h[0] = __floats2half2_rn(g0, g1);
        u.h[1] = __floats2half2_rn(g2, g3);
        u.h[2] = __floats2half2_rn(g4, g5);
        u.h[3] = __floats2half2_rn(g6, g7);
        gated_h[i] = u.f;
    }
}

// ---------------- pass A: per-block LDS histogram over buckets ----------------

__global__ void hist_kernel(const int* __restrict__ row, int* __restrict__ ghist,
                            int E, int NBIN, int NBLK) {
    __shared__ int hist[MAXBIN];
    const int b = blockIdx.x;
    for (int i = threadIdx.x; i < NBIN; i += 256) hist[i] = 0;
    __syncthreads();
    const int base = b * CHUNK;
    #pragma unroll
    for (int it = 0; it < CHUNK / 256; ++it) {
        int e = base + it * 256 + threadIdx.x;
        if (e < E) atomicAdd(&hist[row[e] >> 5], 1);   // bucket = row / RPB
    }
    __syncthreads();
    for (int i = threadIdx.x; i < NBIN; i += 256)
        ghist[(size_t)i * NBLK + b] = hist[i];
}

// ---------------- pass B1: per-bin exclusive scan across blocks ----------------

__global__ void binscan_kernel(const int* __restrict__ ghist, int* __restrict__ gofs,
                               int* __restrict__ btot, int NBIN, int NBLK) {
    const int bin = blockIdx.x * 4 + (threadIdx.x >> 6);
    if (bin >= NBIN) return;
    const int lane = threadIdx.x & 63;
    const int* src = ghist + (size_t)bin * NBLK;
    int* dst = gofs + (size_t)bin * NBLK;
    int carry = 0;
    for (int k = 0; k < NBLK; k += 64) {
        int b = k + lane;
        int v = (b < NBLK) ? src[b] : 0;
        int x = v;
        #pragma unroll
        for (int off = 1; off < 64; off <<= 1) {
            int t = __shfl_up(x, off, 64);
            if (lane >= off) x += t;
        }
        if (b < NBLK) dst[b] = carry + x - v;
        carry += __shfl(x, 63, 64);
    }
    if (lane == 0) btot[bin] = carry;
}

// ---------------- pass B2: single-block scan over bins (n <= 4096 per iter) ----

__global__ void scan_kernel(const int* __restrict__ counts,
                            int* __restrict__ starts, int n) {
    __shared__ int wsum[16];
    __shared__ int wpre[16];
    __shared__ int total_s;
    __shared__ int carry_s;
    const int tid = threadIdx.x;
    const int lane = tid & 63;
    const int wid = tid >> 6;
    if (tid == 0) carry_s = 0;
    __syncthreads();
    for (int base = 0; base < n; base += 4096) {
        int i0 = base + tid * 4;
        int4 v = make_int4(0, 0, 0, 0);
        if (i0 + 0 < n) v.x = counts[i0 + 0];
        if (i0 + 1 < n) v.y = counts[i0 + 1];
        if (i0 + 2 < n) v.z = counts[i0 + 2];
        if (i0 + 3 < n) v.w = counts[i0 + 3];
        int s0 = v.x, s1 = s0 + v.y, s2 = s1 + v.z, s3 = s2 + v.w;
        int x = s3;
        #pragma unroll
        for (int off = 1; off < 64; off <<= 1) {
            int t = __shfl_up(x, off, 64);
            if (lane >= off) x += t;
        }
        if (lane == 63) wsum[wid] = x;
        __syncthreads();
        if (tid < 16) {
            int s = wsum[tid];
            #pragma unroll
            for (int off = 1; off < 16; off <<= 1) {
                int t = __shfl_up(s, off, 64);
                if (tid >= off) s += t;
            }
            wpre[tid] = s - wsum[tid];
            if (tid == 15) total_s = s;
        }
        __syncthreads();
        int pre = carry_s + wpre[wid] + (x - s3);
        if (i0 + 0 < n) starts[i0 + 0] = pre;
        if (i0 + 1 < n) starts[i0 + 1] = pre + s0;
        if (i0 + 2 < n) starts[i0 + 2] = pre + s1;
        if (i0 + 3 < n) starts[i0 + 3] = pre + s2;
        __syncthreads();
        if (tid == 0) carry_s += total_s;
        __syncthreads();
    }
    if (tid == 0) starts[n] = carry_s;
}

// ---------------- pass C: counting-sort scatter (LDS cursors only) ----------------

__global__ void scatter_sort_kernel(const int* __restrict__ row, const int* __restrict__ col,
                                    const float* __restrict__ val,
                                    const int* __restrict__ gofs, const int* __restrict__ bstart,
                                    int2* __restrict__ sorted, int E, int NBIN, int NBLK) {
    __shared__ int cur[MAXBIN];
    const int b = blockIdx.x;
    for (int i = threadIdx.x; i < NBIN; i += 256)
        cur[i] = bstart[i] + gofs[(size_t)i * NBLK + b];
    __syncthreads();
    const int base = b * CHUNK;
    #pragma unroll
    for (int it = 0; it < CHUNK / 256; ++it) {
        int e = base + it * 256 + threadIdx.x;
        if (e < E) {
            int r = row[e];
            int slot = atomicAdd(&cur[r >> 5], 1);
            sorted[slot] = make_int2(col[e] | ((r & (RPB - 1)) << PACK_SHIFT),
                                     __float_as_int(val[e]));
        }
    }
}

// ---------------- pass D: per-bucket accumulate in LDS, fused leaky + store ----

__global__ void __launch_bounds__(256, 8)
acc_kernel(const int* __restrict__ bstart, const int2* __restrict__ sorted,
           const __half2* __restrict__ gated, float* __restrict__ out,
           int N, int NBIN) {
    __shared__ float acc[RPB * DD];     // 16 KB
    const int bin = blockIdx.x;
    for (int i = threadIdx.x; i < RPB * DD; i += 256) acc[i] = 0.f;
    __syncthreads();
    const int ebeg = bstart[bin];
    const int eend = bstart[bin + 1];
    const int w = threadIdx.x >> 6;
    const int lane = threadIdx.x & 63;
    // wave-per-edge, unroll 2 (independent gathers in flight)
    for (int e = ebeg + w; e < eend; e += 8) {
        int2 cv0 = sorted[e];
        int e1 = min(e + 4, eend - 1);
        int2 cv1 = sorted[e1];
        float m1 = (e + 4 < eend) ? 1.f : 0.f;
        float2 g0 = __half22float2(gated[(size_t)(cv0.x & 0xFFFFF) * 64 + lane]);
        float2 g1 = __half22float2(gated[(size_t)(cv1.x & 0xFFFFF) * 64 + lane]);
        float v0 = __int_as_float(cv0.y);
        float v1 = m1 * __int_as_float(cv1.y);
        int rl0 = ((unsigned)cv0.x) >> PACK_SHIFT;
        int rl1 = ((unsigned)cv1.x) >> PACK_SHIFT;
        atomicAdd(&acc[rl0 * DD + 2 * lane + 0], v0 * g0.x);
        atomicAdd(&acc[rl0 * DD + 2 * lane + 1], v0 * g0.y);
        atomicAdd(&acc[rl1 * DD + 2 * lane + 0], v1 * g1.x);
        atomicAdd(&acc[rl1 * DD + 2 * lane + 1], v1 * g1.y);
    }
    __syncthreads();
    const int r0 = bin * RPB;
    for (int idx = threadIdx.x; idx < RPB * (DD / 4); idx += 256) {
        int rl = idx >> 5;          // 32 float4 per row
        int d4 = idx & 31;
        int r = r0 + rl;
        if (r < N) {
            float4 x = *(const float4*)&acc[rl * DD + d4 * 4];
            x.x = x.x > 0.f ? x.x : LEAKY * x.x;
            x.y = x.y > 0.f ? x.y : LEAKY * x.y;
            x.z = x.z > 0.f ? x.z : LEAKY * x.z;
            x.w = x.w > 0.f ? x.w : LEAKY * x.w;
            ((float4*)out)[(size_t)r * (DD / 4) + d4] = x;
        }
    }
}

// ---------------- last-resort fallback (round-1, known-good) ----------------

__global__ void zero4_kernel(float4* __restrict__ out, int n4) {
    int i = blockIdx.x * blockDim.x + threadIdx.x;
    int stride = gridDim.x * blockDim.x;
    float4 z = make_float4(0.f, 0.f, 0.f, 0.f);
    for (; i < n4; i += stride) out[i] = z;
}

__global__ void scatter_fused_kernel(const int* __restrict__ row,
                                     const int* __restrict__ col,
                                     const float* __restrict__ val,
                                     const float* __restrict__ emb,
                                     const float* __restrict__ zs,
                                     float* __restrict__ out, int E) {
    int gid = blockIdx.x * blockDim.x + threadIdx.x;
    int e = gid >> 5;
    if (e >= E) return;
    int lane = gid & 31;
    int r = row[e];
    int c = col[e];
    float v = val[e];
    const float4* ep = (const float4*)(emb + (size_t)c * DD);
    const float4* zp = (const float4*)(zs + (size_t)c * DD);
    float4 ev = ep[lane];
    float4 zv = zp[lane];
    float4 gv;
    gv.x = ev.x * (2.f / (1.f + __expf(-zv.x)) - 1.f);
    gv.y = ev.y * (2.f / (1.f + __expf(-zv.y)) - 1.f);
    gv.z = ev.z * (2.f / (1.f + __expf(-zv.z)) - 1.f);
    gv.w = ev.w * (2.f / (1.f + __expf(-zv.w)) - 1.f);
    float* o = out + (size_t)r * DD + lane * 4;
    atomicAdd(o + 0, v * gv.x);
    atomicAdd(o + 1, v * gv.y);
    atomicAdd(o + 2, v * gv.z);
    atomicAdd(o + 3, v * gv.w);
}

__global__ void leaky_kernel(float4* __restrict__ out, int n4) {
    int i = blockIdx.x * blockDim.x + threadIdx.x;
    int stride = gridDim.x * blockDim.x;
    for (; i < n4; i += stride) {
        float4 x = out[i];
        x.x = x.x > 0.f ? x.x : LEAKY * x.x;
        x.y = x.y > 0.f ? x.y : LEAKY * x.y;
        x.z = x.z > 0.f ? x.z : LEAKY * x.z;
        x.w = x.w > 0.f ? x.w : LEAKY * x.w;
        out[i] = x;
    }
}

// ---------------- launch ----------------

extern "C" void kernel_launch(void* const* d_in, const int* in_sizes, int n_in,
                              void* d_out, int out_size, void* d_ws, size_t ws_size,
                              hipStream_t stream) {
    const int* row_idx = (const int*)d_in[0];
    const int* col_idx = (const int*)d_in[1];
    const float* adj_vals = (const float*)d_in[2];
    const float* embeds = (const float*)d_in[3];
    const float* zishiying = (const float*)d_in[4];
    float* out = (float*)d_out;

    const int E = in_sizes[0];
    const int ND = in_sizes[3];        // N * 128
    const int N = ND / DD;
    const int n4 = ND / 4;
    const int n8 = ND / 8;
    const int NBIN = (N + RPB - 1) / RPB;
    const int NBLK = (E + CHUNK - 1) / CHUNK;

    // ws layout
    char* p = (char*)d_ws;
    __half2* gated = (__half2*)p;          p += (size_t)ND * 2;
    int* ghist = (int*)p;                  p += (size_t)NBIN * NBLK * 4;
    int* gofs = (int*)p;                   p += (size_t)NBIN * NBLK * 4;
    int* btot = (int*)p;                   p += (size_t)NBIN * 4;
    int* bstart = (int*)p;                 p += (size_t)(NBIN + 1) * 4;
    p = (char*)(((uintptr_t)p + 15) & ~(uintptr_t)15);
    int2* sorted = (int2*)p;               p += (size_t)E * 8;
    const size_t need = (size_t)(p - (char*)d_ws);

    const int gb8 = min((n8 + 255) / 256, 2048);

    const bool ok = (NBIN <= MAXBIN) && (NBLK <= MAXBLK) && (N <= (1 << PACK_SHIFT)) &&
                    (ws_size >= need);

    if (ok) {
        hipLaunchKernelGGL(gate_h_kernel, dim3(gb8), dim3(256), 0, stream,
                           (const float4*)embeds, (const float4*)zishiying,
                           (float4*)gated, n8);
        hipLaunchKernelGGL(hist_kernel, dim3(NBLK), dim3(256), 0, stream,
                           row_idx, ghist, E, NBIN, NBLK);
        hipLaunchKernelGGL(binscan_kernel, dim3((NBIN + 3) / 4), dim3(256), 0, stream,
                           ghist, gofs, btot, NBIN, NBLK);
        hipLaunchKernelGGL(scan_kernel, dim3(1), dim3(1024), 0, stream,
                           btot, bstart, NBIN);
        hipLaunchKernelGGL(scatter_sort_kernel, dim3(NBLK), dim3(256), 0, stream,
                           row_idx, col_idx, adj_vals, gofs, bstart, sorted, E, NBIN, NBLK);
        hipLaunchKernelGGL(acc_kernel, dim3(NBIN), dim3(256), 0, stream,
                           bstart, sorted, gated, out, N, NBIN);
        return;
    }

    // ---------- last-resort atomic path ----------
    const int gb = min((n4 + 255) / 256, 2048);
    hipLaunchKernelGGL(zero4_kernel, dim3(gb), dim3(256), 0, stream, (float4*)out, n4);
    {
        long long total = (long long)E * 32;
        int sblocks = (int)((total + 255) / 256);
        hipLaunchKernelGGL(scatter_fused_kernel, dim3(sblocks), dim3(256), 0, stream,
                           row_idx, col_idx, adj_vals, embeds, zishiying, out, E);
    }
    hipLaunchKernelGGL(leaky_kernel, dim3(gb), dim3(256), 0, stream, (float4*)out, n4);
}

// Round 7
// 150.144 us; speedup vs baseline: 7.8121x; 7.8121x over previous
//
#include <hip/hip_runtime.h>
#include <hip/hip_fp16.h>
#include <math.h>

#define DD 128
#define LEAKY 0.5f
#define RPB 32              // rows per bucket
#define MAXBIN 3200         // >= ceil(N/RPB)
#define CHUNK 8192          // edges per partition block
#define MAXBLK 256          // >= ceil(E/CHUNK)
#define PACK_SHIFT 20       // col in low 20 bits, row_local above

// ---------------- gate: fp16, 8 floats -> 8 halves per iter ----------------

__global__ void gate_h_kernel(const float4* __restrict__ emb,
                              const float4* __restrict__ zs,
                              float4* __restrict__ gated_h, int n8) {
    int i = blockIdx.x * blockDim.x + threadIdx.x;
    int stride = gridDim.x * blockDim.x;
    for (; i < n8; i += stride) {
        float4 e0 = emb[2 * i], e1 = emb[2 * i + 1];
        float4 z0 = zs[2 * i], z1 = zs[2 * i + 1];
        float g0 = e0.x * (2.f / (1.f + __expf(-z0.x)) - 1.f);
        float g1 = e0.y * (2.f / (1.f + __expf(-z0.y)) - 1.f);
        float g2 = e0.z * (2.f / (1.f + __expf(-z0.z)) - 1.f);
        float g3 = e0.w * (2.f / (1.f + __expf(-z0.w)) - 1.f);
        float g4 = e1.x * (2.f / (1.f + __expf(-z1.x)) - 1.f);
        float g5 = e1.y * (2.f / (1.f + __expf(-z1.y)) - 1.f);
        float g6 = e1.z * (2.f / (1.f + __expf(-z1.z)) - 1.f);
        float g7 = e1.w * (2.f / (1.f + __expf(-z1.w)) - 1.f);
        union { __half2 h[4]; float4 f; } u;
        u.h[0] = __floats2half2_rn(g0, g1);
        u.h[1] = __floats2half2_rn(g2, g3);
        u.h[2] = __floats2half2_rn(g4, g5);
        u.h[3] = __floats2half2_rn(g6, g7);
        gated_h[i] = u.f;
    }
}

// ---------------- pass A: per-block LDS histogram over buckets ----------------

__global__ void hist_kernel(const int* __restrict__ row, int* __restrict__ ghist,
                            int E, int NBIN, int NBLK) {
    __shared__ int hist[MAXBIN];
    const int b = blockIdx.x;
    for (int i = threadIdx.x; i < NBIN; i += 256) hist[i] = 0;
    __syncthreads();
    const int base = b * CHUNK;
    #pragma unroll
    for (int it = 0; it < CHUNK / 256; ++it) {
        int e = base + it * 256 + threadIdx.x;
        if (e < E) atomicAdd(&hist[row[e] >> 5], 1);   // bucket = row / RPB
    }
    __syncthreads();
    for (int i = threadIdx.x; i < NBIN; i += 256)
        ghist[(size_t)i * NBLK + b] = hist[i];
}

// ---------------- pass B1: per-bin exclusive scan across blocks ----------------

__global__ void binscan_kernel(const int* __restrict__ ghist, int* __restrict__ gofs,
                               int* __restrict__ btot, int NBIN, int NBLK) {
    const int bin = blockIdx.x * 4 + (threadIdx.x >> 6);
    if (bin >= NBIN) return;
    const int lane = threadIdx.x & 63;
    const int* src = ghist + (size_t)bin * NBLK;
    int* dst = gofs + (size_t)bin * NBLK;
    int carry = 0;
    for (int k = 0; k < NBLK; k += 64) {
        int b = k + lane;
        int v = (b < NBLK) ? src[b] : 0;
        int x = v;
        #pragma unroll
        for (int off = 1; off < 64; off <<= 1) {
            int t = __shfl_up(x, off, 64);
            if (lane >= off) x += t;
        }
        if (b < NBLK) dst[b] = carry + x - v;
        carry += __shfl(x, 63, 64);
    }
    if (lane == 0) btot[bin] = carry;
}

// ---------------- pass B2: single-block scan over bins ----------------

__global__ void scan_kernel(const int* __restrict__ counts,
                            int* __restrict__ starts, int n) {
    __shared__ int wsum[16];
    __shared__ int wpre[16];
    __shared__ int total_s;
    __shared__ int carry_s;
    const int tid = threadIdx.x;
    const int lane = tid & 63;
    const int wid = tid >> 6;
    if (tid == 0) carry_s = 0;
    __syncthreads();
    for (int base = 0; base < n; base += 4096) {
        int i0 = base + tid * 4;
        int4 v = make_int4(0, 0, 0, 0);
        if (i0 + 0 < n) v.x = counts[i0 + 0];
        if (i0 + 1 < n) v.y = counts[i0 + 1];
        if (i0 + 2 < n) v.z = counts[i0 + 2];
        if (i0 + 3 < n) v.w = counts[i0 + 3];
        int s0 = v.x, s1 = s0 + v.y, s2 = s1 + v.z, s3 = s2 + v.w;
        int x = s3;
        #pragma unroll
        for (int off = 1; off < 64; off <<= 1) {
            int t = __shfl_up(x, off, 64);
            if (lane >= off) x += t;
        }
        if (lane == 63) wsum[wid] = x;
        __syncthreads();
        if (tid < 16) {
            int s = wsum[tid];
            #pragma unroll
            for (int off = 1; off < 16; off <<= 1) {
                int t = __shfl_up(s, off, 64);
                if (tid >= off) s += t;
            }
            wpre[tid] = s - wsum[tid];
            if (tid == 15) total_s = s;
        }
        __syncthreads();
        int pre = carry_s + wpre[wid] + (x - s3);
        if (i0 + 0 < n) starts[i0 + 0] = pre;
        if (i0 + 1 < n) starts[i0 + 1] = pre + s0;
        if (i0 + 2 < n) starts[i0 + 2] = pre + s1;
        if (i0 + 3 < n) starts[i0 + 3] = pre + s2;
        __syncthreads();
        if (tid == 0) carry_s += total_s;
        __syncthreads();
    }
    if (tid == 0) starts[n] = carry_s;
}

// ---------------- pass C: counting-sort scatter into buckets (LDS cursors) ----

__global__ void scatter_sort_kernel(const int* __restrict__ row, const int* __restrict__ col,
                                    const float* __restrict__ val,
                                    const int* __restrict__ gofs, const int* __restrict__ bstart,
                                    int2* __restrict__ sorted, int E, int NBIN, int NBLK) {
    __shared__ int cur[MAXBIN];
    const int b = blockIdx.x;
    for (int i = threadIdx.x; i < NBIN; i += 256)
        cur[i] = bstart[i] + gofs[(size_t)i * NBLK + b];
    __syncthreads();
    const int base = b * CHUNK;
    #pragma unroll
    for (int it = 0; it < CHUNK / 256; ++it) {
        int e = base + it * 256 + threadIdx.x;
        if (e < E) {
            int r = row[e];
            int slot = atomicAdd(&cur[r >> 5], 1);
            sorted[slot] = make_int2(col[e] | ((r & (RPB - 1)) << PACK_SHIFT),
                                     __float_as_int(val[e]));
        }
    }
}

// ---------------- pass D: within-bucket row sort -> full CSR + rowstart ------

__global__ void rowsort_kernel(const int2* __restrict__ sorted,
                               const int* __restrict__ bstart,
                               int2* __restrict__ csr,
                               int* __restrict__ rowstart, int N, int NBIN, int E) {
    __shared__ int cnt[RPB];
    __shared__ int cur[RPB];
    const int bin = blockIdx.x;
    const int tid = threadIdx.x;
    if (tid < RPB) cnt[tid] = 0;
    __syncthreads();
    const int beg = bstart[bin], end = bstart[bin + 1];
    for (int e = beg + tid; e < end; e += 256) {
        int rl = ((unsigned)sorted[e].x) >> PACK_SHIFT;
        atomicAdd(&cnt[rl], 1);
    }
    __syncthreads();
    if (tid < RPB) {                 // wave 0: exclusive scan over 32 counts
        int v = cnt[tid];
        int x = v;
        #pragma unroll
        for (int off = 1; off < RPB; off <<= 1) {
            int t = __shfl_up(x, off, RPB);
            if (tid >= off) x += t;
        }
        int excl = x - v;
        cur[tid] = beg + excl;
        int r = bin * RPB + tid;
        if (r < N) rowstart[r] = beg + excl;
    }
    if (tid == 0 && bin == 0) rowstart[N] = E;
    __syncthreads();
    for (int e = beg + tid; e < end; e += 256) {
        int2 cv = sorted[e];
        int rl = ((unsigned)cv.x) >> PACK_SHIFT;
        int slot = atomicAdd(&cur[rl], 1);
        csr[slot] = make_int2(cv.x & ((1 << PACK_SHIFT) - 1), cv.y);
    }
}

// ---------------- pass E: one wave per row, fp16 gather, fused leaky ---------

__global__ void gather_h_kernel(const int* __restrict__ starts,
                                const int2* __restrict__ csr,
                                const __half2* __restrict__ gated,
                                float* __restrict__ out, int N) {
    int gid = blockIdx.x * blockDim.x + threadIdx.x;
    int r = gid >> 6;
    if (r >= N) return;
    int lane = gid & 63;
    int beg = __builtin_amdgcn_readfirstlane(starts[r]);
    int end = __builtin_amdgcn_readfirstlane(starts[r + 1]);
    float2 acc = make_float2(0.f, 0.f);
    int j = beg;
    for (; j + 3 < end; j += 4) {
        int2 cv0 = csr[j];
        int2 cv1 = csr[j + 1];
        int2 cv2 = csr[j + 2];
        int2 cv3 = csr[j + 3];
        float2 g0 = __half22float2(gated[(size_t)cv0.x * 64 + lane]);
        float2 g1 = __half22float2(gated[(size_t)cv1.x * 64 + lane]);
        float2 g2 = __half22float2(gated[(size_t)cv2.x * 64 + lane]);
        float2 g3 = __half22float2(gated[(size_t)cv3.x * 64 + lane]);
        float v0 = __int_as_float(cv0.y);
        float v1 = __int_as_float(cv1.y);
        float v2 = __int_as_float(cv2.y);
        float v3 = __int_as_float(cv3.y);
        acc.x += v0 * g0.x; acc.y += v0 * g0.y;
        acc.x += v1 * g1.x; acc.y += v1 * g1.y;
        acc.x += v2 * g2.x; acc.y += v2 * g2.y;
        acc.x += v3 * g3.x; acc.y += v3 * g3.y;
    }
    for (; j < end; ++j) {
        int2 cv = csr[j];
        float2 g = __half22float2(gated[(size_t)cv.x * 64 + lane]);
        float v = __int_as_float(cv.y);
        acc.x += v * g.x; acc.y += v * g.y;
    }
    acc.x = acc.x > 0.f ? acc.x : LEAKY * acc.x;
    acc.y = acc.y > 0.f ? acc.y : LEAKY * acc.y;
    ((float2*)out)[(size_t)r * 64 + lane] = acc;
}

// ---------------- last-resort fallback (round-1, known-good, ws-free) --------

__global__ void zero4_kernel(float4* __restrict__ out, int n4) {
    int i = blockIdx.x * blockDim.x + threadIdx.x;
    int stride = gridDim.x * blockDim.x;
    float4 z = make_float4(0.f, 0.f, 0.f, 0.f);
    for (; i < n4; i += stride) out[i] = z;
}

__global__ void scatter_fused_kernel(const int* __restrict__ row,
                                     const int* __restrict__ col,
                                     const float* __restrict__ val,
                                     const float* __restrict__ emb,
                                     const float* __restrict__ zs,
                                     float* __restrict__ out, int E) {
    int gid = blockIdx.x * blockDim.x + threadIdx.x;
    int e = gid >> 5;
    if (e >= E) return;
    int lane = gid & 31;
    int r = row[e];
    int c = col[e];
    float v = val[e];
    const float4* ep = (const float4*)(emb + (size_t)c * DD);
    const float4* zp = (const float4*)(zs + (size_t)c * DD);
    float4 ev = ep[lane];
    float4 zv = zp[lane];
    float4 gv;
    gv.x = ev.x * (2.f / (1.f + __expf(-zv.x)) - 1.f);
    gv.y = ev.y * (2.f / (1.f + __expf(-zv.y)) - 1.f);
    gv.z = ev.z * (2.f / (1.f + __expf(-zv.z)) - 1.f);
    gv.w = ev.w * (2.f / (1.f + __expf(-zv.w)) - 1.f);
    float* o = out + (size_t)r * DD + lane * 4;
    atomicAdd(o + 0, v * gv.x);
    atomicAdd(o + 1, v * gv.y);
    atomicAdd(o + 2, v * gv.z);
    atomicAdd(o + 3, v * gv.w);
}

__global__ void leaky_kernel(float4* __restrict__ out, int n4) {
    int i = blockIdx.x * blockDim.x + threadIdx.x;
    int stride = gridDim.x * blockDim.x;
    for (; i < n4; i += stride) {
        float4 x = out[i];
        x.x = x.x > 0.f ? x.x : LEAKY * x.x;
        x.y = x.y > 0.f ? x.y : LEAKY * x.y;
        x.z = x.z > 0.f ? x.z : LEAKY * x.z;
        x.w = x.w > 0.f ? x.w : LEAKY * x.w;
        out[i] = x;
    }
}

// ---------------- launch ----------------

extern "C" void kernel_launch(void* const* d_in, const int* in_sizes, int n_in,
                              void* d_out, int out_size, void* d_ws, size_t ws_size,
                              hipStream_t stream) {
    const int* row_idx = (const int*)d_in[0];
    const int* col_idx = (const int*)d_in[1];
    const float* adj_vals = (const float*)d_in[2];
    const float* embeds = (const float*)d_in[3];
    const float* zishiying = (const float*)d_in[4];
    float* out = (float*)d_out;

    const int E = in_sizes[0];
    const int ND = in_sizes[3];        // N * 128
    const int N = ND / DD;
    const int n4 = ND / 4;
    const int n8 = ND / 8;
    const int NBIN = (N + RPB - 1) / RPB;
    const int NBLK = (E + CHUNK - 1) / CHUNK;

    // ws layout
    char* p = (char*)d_ws;
    __half2* gated = (__half2*)p;          p += (size_t)ND * 2;
    int* ghist = (int*)p;                  p += (size_t)NBIN * NBLK * 4;
    int* gofs = (int*)p;                   p += (size_t)NBIN * NBLK * 4;
    int* btot = (int*)p;                   p += (size_t)NBIN * 4;
    int* bstart = (int*)p;                 p += (size_t)(NBIN + 1) * 4;
    int* rowstart = (int*)p;               p += (size_t)(N + 1) * 4;
    p = (char*)(((uintptr_t)p + 15) & ~(uintptr_t)15);
    int2* sorted = (int2*)p;               p += (size_t)E * 8;
    int2* csr = (int2*)p;                  p += (size_t)E * 8;
    const size_t need = (size_t)(p - (char*)d_ws);

    const int gb8 = min((n8 + 255) / 256, 2048);

    const bool ok = (NBIN <= MAXBIN) && (NBLK <= MAXBLK) && (N <= (1 << PACK_SHIFT)) &&
                    (ws_size >= need);

    if (ok) {
        hipLaunchKernelGGL(gate_h_kernel, dim3(gb8), dim3(256), 0, stream,
                           (const float4*)embeds, (const float4*)zishiying,
                           (float4*)gated, n8);
        hipLaunchKernelGGL(hist_kernel, dim3(NBLK), dim3(256), 0, stream,
                           row_idx, ghist, E, NBIN, NBLK);
        hipLaunchKernelGGL(binscan_kernel, dim3((NBIN + 3) / 4), dim3(256), 0, stream,
                           ghist, gofs, btot, NBIN, NBLK);
        hipLaunchKernelGGL(scan_kernel, dim3(1), dim3(1024), 0, stream,
                           btot, bstart, NBIN);
        hipLaunchKernelGGL(scatter_sort_kernel, dim3(NBLK), dim3(256), 0, stream,
                           row_idx, col_idx, adj_vals, gofs, bstart, sorted, E, NBIN, NBLK);
        hipLaunchKernelGGL(rowsort_kernel, dim3(NBIN), dim3(256), 0, stream,
                           sorted, bstart, csr, rowstart, N, NBIN, E);
        long long total = (long long)N * 64;
        int blocks = (int)((total + 255) / 256);
        hipLaunchKernelGGL(gather_h_kernel, dim3(blocks), dim3(256), 0, stream,
                           rowstart, csr, gated, out, N);
        return;
    }

    // ---------- last-resort atomic path ----------
    const int gb = min((n4 + 255) / 256, 2048);
    hipLaunchKernelGGL(zero4_kernel, dim3(gb), dim3(256), 0, stream, (float4*)out, n4);
    {
        long long total = (long long)E * 32;
        int sblocks = (int)((total + 255) / 256);
        hipLaunchKernelGGL(scatter_fused_kernel, dim3(sblocks), dim3(256), 0, stream,
                           row_idx, col_idx, adj_vals, embeds, zishiying, out, E);
    }
    hipLaunchKernelGGL(leaky_kernel, dim3(gb), dim3(256), 0, stream, (float4*)out, n4);
}

// Round 8
// 144.296 us; speedup vs baseline: 8.1288x; 1.0405x over previous
//
#include <hip/hip_runtime.h>
#include <hip/hip_fp16.h>
#include <math.h>

#define DD 128
#define LEAKY 0.5f
#define RPB 128             // rows per bucket (power of 2)
#define RPB_SHIFT 7
#define MAXBIN 1024         // >= ceil(N/RPB); LDS hist/cursor = 4 KB
#define CHUNK 2048          // edges per partition block
#define MAXBLK 1024         // >= ceil(E/CHUNK)
#define PACK_SHIFT 20       // col in low 20 bits, row_local (7b) above

// ---------------- gate: fp16, 8 floats -> 8 halves per iter ----------------

__global__ void gate_h_kernel(const float4* __restrict__ emb,
                              const float4* __restrict__ zs,
                              float4* __restrict__ gated_h, int n8) {
    int i = blockIdx.x * blockDim.x + threadIdx.x;
    int stride = gridDim.x * blockDim.x;
    for (; i < n8; i += stride) {
        float4 e0 = emb[2 * i], e1 = emb[2 * i + 1];
        float4 z0 = zs[2 * i], z1 = zs[2 * i + 1];
        float g0 = e0.x * (2.f / (1.f + __expf(-z0.x)) - 1.f);
        float g1 = e0.y * (2.f / (1.f + __expf(-z0.y)) - 1.f);
        float g2 = e0.z * (2.f / (1.f + __expf(-z0.z)) - 1.f);
        float g3 = e0.w * (2.f / (1.f + __expf(-z0.w)) - 1.f);
        float g4 = e1.x * (2.f / (1.f + __expf(-z1.x)) - 1.f);
        float g5 = e1.y * (2.f / (1.f + __expf(-z1.y)) - 1.f);
        float g6 = e1.z * (2.f / (1.f + __expf(-z1.z)) - 1.f);
        float g7 = e1.w * (2.f / (1.f + __expf(-z1.w)) - 1.f);
        union { __half2 h[4]; float4 f; } u;
        u.h[0] = __floats2half2_rn(g0, g1);
        u.h[1] = __floats2half2_rn(g2, g3);
        u.h[2] = __floats2half2_rn(g4, g5);
        u.h[3] = __floats2half2_rn(g6, g7);
        gated_h[i] = u.f;
    }
}

// ---------------- pass A: per-block LDS histogram over buckets ----------------

__global__ void hist_kernel(const int* __restrict__ row, int* __restrict__ ghist,
                            int E, int NBIN, int NBLK) {
    __shared__ int hist[MAXBIN];
    const int b = blockIdx.x;
    for (int i = threadIdx.x; i < NBIN; i += 256) hist[i] = 0;
    __syncthreads();
    const int base = b * CHUNK;
    #pragma unroll
    for (int it = 0; it < CHUNK / 256; ++it) {
        int e = base + it * 256 + threadIdx.x;
        if (e < E) atomicAdd(&hist[row[e] >> RPB_SHIFT], 1);
    }
    __syncthreads();
    for (int i = threadIdx.x; i < NBIN; i += 256)
        ghist[(size_t)i * NBLK + b] = hist[i];
}

// ---------------- pass B1: per-bin exclusive scan across blocks ----------------

__global__ void binscan_kernel(const int* __restrict__ ghist, int* __restrict__ gofs,
                               int* __restrict__ btot, int NBIN, int NBLK) {
    const int bin = blockIdx.x * 4 + (threadIdx.x >> 6);
    if (bin >= NBIN) return;
    const int lane = threadIdx.x & 63;
    const int* src = ghist + (size_t)bin * NBLK;
    int* dst = gofs + (size_t)bin * NBLK;
    int carry = 0;
    for (int k = 0; k < NBLK; k += 64) {
        int b = k + lane;
        int v = (b < NBLK) ? src[b] : 0;
        int x = v;
        #pragma unroll
        for (int off = 1; off < 64; off <<= 1) {
            int t = __shfl_up(x, off, 64);
            if (lane >= off) x += t;
        }
        if (b < NBLK) dst[b] = carry + x - v;
        carry += __shfl(x, 63, 64);
    }
    if (lane == 0) btot[bin] = carry;
}

// ---------------- pass B2: single-block scan over bins ----------------

__global__ void scan_kernel(const int* __restrict__ counts,
                            int* __restrict__ starts, int n) {
    __shared__ int wsum[16];
    __shared__ int wpre[16];
    __shared__ int total_s;
    __shared__ int carry_s;
    const int tid = threadIdx.x;
    const int lane = tid & 63;
    const int wid = tid >> 6;
    if (tid == 0) carry_s = 0;
    __syncthreads();
    for (int base = 0; base < n; base += 4096) {
        int i0 = base + tid * 4;
        int4 v = make_int4(0, 0, 0, 0);
        if (i0 + 0 < n) v.x = counts[i0 + 0];
        if (i0 + 1 < n) v.y = counts[i0 + 1];
        if (i0 + 2 < n) v.z = counts[i0 + 2];
        if (i0 + 3 < n) v.w = counts[i0 + 3];
        int s0 = v.x, s1 = s0 + v.y, s2 = s1 + v.z, s3 = s2 + v.w;
        int x = s3;
        #pragma unroll
        for (int off = 1; off < 64; off <<= 1) {
            int t = __shfl_up(x, off, 64);
            if (lane >= off) x += t;
        }
        if (lane == 63) wsum[wid] = x;
        __syncthreads();
        if (tid < 16) {
            int s = wsum[tid];
            #pragma unroll
            for (int off = 1; off < 16; off <<= 1) {
                int t = __shfl_up(s, off, 64);
                if (tid >= off) s += t;
            }
            wpre[tid] = s - wsum[tid];
            if (tid == 15) total_s = s;
        }
        __syncthreads();
        int pre = carry_s + wpre[wid] + (x - s3);
        if (i0 + 0 < n) starts[i0 + 0] = pre;
        if (i0 + 1 < n) starts[i0 + 1] = pre + s0;
        if (i0 + 2 < n) starts[i0 + 2] = pre + s1;
        if (i0 + 3 < n) starts[i0 + 3] = pre + s2;
        __syncthreads();
        if (tid == 0) carry_s += total_s;
        __syncthreads();
    }
    if (tid == 0) starts[n] = carry_s;
}

// ---------------- pass C: counting-sort scatter into buckets (LDS cursors) ----

__global__ void scatter_sort_kernel(const int* __restrict__ row, const int* __restrict__ col,
                                    const float* __restrict__ val,
                                    const int* __restrict__ gofs, const int* __restrict__ bstart,
                                    int2* __restrict__ sorted, int E, int NBIN, int NBLK) {
    __shared__ int cur[MAXBIN];
    const int b = blockIdx.x;
    for (int i = threadIdx.x; i < NBIN; i += 256)
        cur[i] = bstart[i] + gofs[(size_t)i * NBLK + b];
    __syncthreads();
    const int base = b * CHUNK;
    #pragma unroll
    for (int it = 0; it < CHUNK / 256; ++it) {
        int e = base + it * 256 + threadIdx.x;
        if (e < E) {
            int r = row[e];
            int slot = atomicAdd(&cur[r >> RPB_SHIFT], 1);
            sorted[slot] = make_int2(col[e] | ((r & (RPB - 1)) << PACK_SHIFT),
                                     __float_as_int(val[e]));
        }
    }
}

// ---------------- pass D: within-bucket row sort -> full CSR + rowstart ------

__global__ void rowsort_kernel(const int2* __restrict__ sorted,
                               const int* __restrict__ bstart,
                               int2* __restrict__ csr,
                               int* __restrict__ rowstart, int N, int NBIN, int E) {
    __shared__ int cnt[RPB];
    __shared__ int cur[RPB];
    __shared__ int wsum[4];
    const int bin = blockIdx.x;
    const int tid = threadIdx.x;
    const int lane = tid & 63;
    const int wid = tid >> 6;
    for (int i = tid; i < RPB; i += 256) cnt[i] = 0;
    __syncthreads();
    const int beg = bstart[bin], end = bstart[bin + 1];
    for (int e = beg + tid; e < end; e += 256) {
        int rl = ((unsigned)sorted[e].x) >> PACK_SHIFT;
        atomicAdd(&cnt[rl], 1);
    }
    __syncthreads();
    // exclusive scan over RPB=128 counts using waves 0..1 (all threads run uniform code)
    int v = (tid < RPB) ? cnt[tid] : 0;
    int x = v;
    #pragma unroll
    for (int off = 1; off < 64; off <<= 1) {
        int t = __shfl_up(x, off, 64);
        if (lane >= off) x += t;
    }
    if (lane == 63) wsum[wid] = x;
    __syncthreads();
    int base = 0;
    #pragma unroll
    for (int w = 0; w < 4; ++w) if (w < wid) base += wsum[w];
    int excl = base + x - v;
    if (tid < RPB) {
        cur[tid] = beg + excl;
        int r = bin * RPB + tid;
        if (r < N) rowstart[r] = beg + excl;
    }
    if (tid == 0 && bin == 0) rowstart[N] = E;
    __syncthreads();
    for (int e = beg + tid; e < end; e += 256) {
        int2 cv = sorted[e];
        int rl = ((unsigned)cv.x) >> PACK_SHIFT;
        int slot = atomicAdd(&cur[rl], 1);
        csr[slot] = make_int2(cv.x & ((1 << PACK_SHIFT) - 1), cv.y);
    }
}

// ---------------- pass E: one wave per row, fp16 gather, fused leaky ---------

__global__ void gather_h_kernel(const int* __restrict__ starts,
                                const int2* __restrict__ csr,
                                const __half2* __restrict__ gated,
                                float* __restrict__ out, int N) {
    int gid = blockIdx.x * blockDim.x + threadIdx.x;
    int r = gid >> 6;
    if (r >= N) return;
    int lane = gid & 63;
    int beg = __builtin_amdgcn_readfirstlane(starts[r]);
    int end = __builtin_amdgcn_readfirstlane(starts[r + 1]);
    float2 acc = make_float2(0.f, 0.f);
    int j = beg;
    for (; j + 3 < end; j += 4) {
        int2 cv0 = csr[j];
        int2 cv1 = csr[j + 1];
        int2 cv2 = csr[j + 2];
        int2 cv3 = csr[j + 3];
        float2 g0 = __half22float2(gated[(size_t)cv0.x * 64 + lane]);
        float2 g1 = __half22float2(gated[(size_t)cv1.x * 64 + lane]);
        float2 g2 = __half22float2(gated[(size_t)cv2.x * 64 + lane]);
        float2 g3 = __half22float2(gated[(size_t)cv3.x * 64 + lane]);
        float v0 = __int_as_float(cv0.y);
        float v1 = __int_as_float(cv1.y);
        float v2 = __int_as_float(cv2.y);
        float v3 = __int_as_float(cv3.y);
        acc.x += v0 * g0.x; acc.y += v0 * g0.y;
        acc.x += v1 * g1.x; acc.y += v1 * g1.y;
        acc.x += v2 * g2.x; acc.y += v2 * g2.y;
        acc.x += v3 * g3.x; acc.y += v3 * g3.y;
    }
    for (; j < end; ++j) {
        int2 cv = csr[j];
        float2 g = __half22float2(gated[(size_t)cv.x * 64 + lane]);
        float v = __int_as_float(cv.y);
        acc.x += v * g.x; acc.y += v * g.y;
    }
    acc.x = acc.x > 0.f ? acc.x : LEAKY * acc.x;
    acc.y = acc.y > 0.f ? acc.y : LEAKY * acc.y;
    ((float2*)out)[(size_t)r * 64 + lane] = acc;
}

// ---------------- last-resort fallback (round-1, known-good, ws-free) --------

__global__ void zero4_kernel(float4* __restrict__ out, int n4) {
    int i = blockIdx.x * blockDim.x + threadIdx.x;
    int stride = gridDim.x * blockDim.x;
    float4 z = make_float4(0.f, 0.f, 0.f, 0.f);
    for (; i < n4; i += stride) out[i] = z;
}

__global__ void scatter_fused_kernel(const int* __restrict__ row,
                                     const int* __restrict__ col,
                                     const float* __restrict__ val,
                                     const float* __restrict__ emb,
                                     const float* __restrict__ zs,
                                     float* __restrict__ out, int E) {
    int gid = blockIdx.x * blockDim.x + threadIdx.x;
    int e = gid >> 5;
    if (e >= E) return;
    int lane = gid & 31;
    int r = row[e];
    int c = col[e];
    float v = val[e];
    const float4* ep = (const float4*)(emb + (size_t)c * DD);
    const float4* zp = (const float4*)(zs + (size_t)c * DD);
    float4 ev = ep[lane];
    float4 zv = zp[lane];
    float4 gv;
    gv.x = ev.x * (2.f / (1.f + __expf(-zv.x)) - 1.f);
    gv.y = ev.y * (2.f / (1.f + __expf(-zv.y)) - 1.f);
    gv.z = ev.z * (2.f / (1.f + __expf(-zv.z)) - 1.f);
    gv.w = ev.w * (2.f / (1.f + __expf(-zv.w)) - 1.f);
    float* o = out + (size_t)r * DD + lane * 4;
    atomicAdd(o + 0, v * gv.x);
    atomicAdd(o + 1, v * gv.y);
    atomicAdd(o + 2, v * gv.z);
    atomicAdd(o + 3, v * gv.w);
}

__global__ void leaky_kernel(float4* __restrict__ out, int n4) {
    int i = blockIdx.x * blockDim.x + threadIdx.x;
    int stride = gridDim.x * blockDim.x;
    for (; i < n4; i += stride) {
        float4 x = out[i];
        x.x = x.x > 0.f ? x.x : LEAKY * x.x;
        x.y = x.y > 0.f ? x.y : LEAKY * x.y;
        x.z = x.z > 0.f ? x.z : LEAKY * x.z;
        x.w = x.w > 0.f ? x.w : LEAKY * x.w;
        out[i] = x;
    }
}

// ---------------- launch ----------------

extern "C" void kernel_launch(void* const* d_in, const int* in_sizes, int n_in,
                              void* d_out, int out_size, void* d_ws, size_t ws_size,
                              hipStream_t stream) {
    const int* row_idx = (const int*)d_in[0];
    const int* col_idx = (const int*)d_in[1];
    const float* adj_vals = (const float*)d_in[2];
    const float* embeds = (const float*)d_in[3];
    const float* zishiying = (const float*)d_in[4];
    float* out = (float*)d_out;

    const int E = in_sizes[0];
    const int ND = in_sizes[3];        // N * 128
    const int N = ND / DD;
    const int n4 = ND / 4;
    const int n8 = ND / 8;
    const int NBIN = (N + RPB - 1) / RPB;
    const int NBLK = (E + CHUNK - 1) / CHUNK;

    // ws layout
    char* p = (char*)d_ws;
    __half2* gated = (__half2*)p;          p += (size_t)ND * 2;
    int* ghist = (int*)p;                  p += (size_t)NBIN * NBLK * 4;
    int* gofs = (int*)p;                   p += (size_t)NBIN * NBLK * 4;
    int* btot = (int*)p;                   p += (size_t)NBIN * 4;
    int* bstart = (int*)p;                 p += (size_t)(NBIN + 1) * 4;
    int* rowstart = (int*)p;               p += (size_t)(N + 1) * 4;
    p = (char*)(((uintptr_t)p + 15) & ~(uintptr_t)15);
    int2* sorted = (int2*)p;               p += (size_t)E * 8;
    int2* csr = (int2*)p;                  p += (size_t)E * 8;
    const size_t need = (size_t)(p - (char*)d_ws);

    const int gb8 = min((n8 + 255) / 256, 2048);

    const bool ok = (NBIN <= MAXBIN) && (NBLK <= MAXBLK) && (N <= (1 << PACK_SHIFT)) &&
                    (ws_size >= need);

    if (ok) {
        hipLaunchKernelGGL(gate_h_kernel, dim3(gb8), dim3(256), 0, stream,
                           (const float4*)embeds, (const float4*)zishiying,
                           (float4*)gated, n8);
        hipLaunchKernelGGL(hist_kernel, dim3(NBLK), dim3(256), 0, stream,
                           row_idx, ghist, E, NBIN, NBLK);
        hipLaunchKernelGGL(binscan_kernel, dim3((NBIN + 3) / 4), dim3(256), 0, stream,
                           ghist, gofs, btot, NBIN, NBLK);
        hipLaunchKernelGGL(scan_kernel, dim3(1), dim3(1024), 0, stream,
                           btot, bstart, NBIN);
        hipLaunchKernelGGL(scatter_sort_kernel, dim3(NBLK), dim3(256), 0, stream,
                           row_idx, col_idx, adj_vals, gofs, bstart, sorted, E, NBIN, NBLK);
        hipLaunchKernelGGL(rowsort_kernel, dim3(NBIN), dim3(256), 0, stream,
                           sorted, bstart, csr, rowstart, N, NBIN, E);
        long long total = (long long)N * 64;
        int blocks = (int)((total + 255) / 256);
        hipLaunchKernelGGL(gather_h_kernel, dim3(blocks), dim3(256), 0, stream,
                           rowstart, csr, gated, out, N);
        return;
    }

    // ---------- last-resort atomic path ----------
    const int gb = min((n4 + 255) / 256, 2048);
    hipLaunchKernelGGL(zero4_kernel, dim3(gb), dim3(256), 0, stream, (float4*)out, n4);
    {
        long long total = (long long)E * 32;
        int sblocks = (int)((total + 255) / 256);
        hipLaunchKernelGGL(scatter_fused_kernel, dim3(sblocks), dim3(256), 0, stream,
                           row_idx, col_idx, adj_vals, embeds, zishiying, out, E);
    }
    hipLaunchKernelGGL(leaky_kernel, dim3(gb), dim3(256), 0, stream, (float4*)out, n4);
}

// Round 9
// 144.087 us; speedup vs baseline: 8.1405x; 1.0014x over previous
//
#include <hip/hip_runtime.h>
#include <hip/hip_fp16.h>
#include <math.h>

#define DD 128
#define LEAKY 0.5f
#define RPB 128             // rows per bucket (power of 2)
#define RPB_SHIFT 7
#define MAXBIN 1024         // >= ceil(N/RPB); LDS hist/cursor = 4 KB
#define CHUNK 2048          // edges per partition block
#define MAXBLK 1024         // >= ceil(E/CHUNK)
#define PACK_SHIFT 20       // col in low 20 bits, row_local (7b) above

// ---------------- fused pass: gate (fp16) + per-block bucket histogram -------

__global__ void gatehist_kernel(const float4* __restrict__ emb,
                                const float4* __restrict__ zs,
                                float4* __restrict__ gated_h, int n8,
                                const int* __restrict__ row, int* __restrict__ ghist,
                                int E, int NBIN, int NBLK) {
    __shared__ int hist[MAXBIN];
    const int b = blockIdx.x;
    if (b < NBLK) {
        for (int i = threadIdx.x; i < NBIN; i += 256) hist[i] = 0;
        __syncthreads();
        const int base = b * CHUNK;
        #pragma unroll
        for (int it = 0; it < CHUNK / 256; ++it) {
            int e = base + it * 256 + threadIdx.x;
            if (e < E) atomicAdd(&hist[row[e] >> RPB_SHIFT], 1);
        }
        __syncthreads();
        for (int i = threadIdx.x; i < NBIN; i += 256)
            ghist[(size_t)i * NBLK + b] = hist[i];
    }
    // gate slice (grid-stride over all blocks)
    int i = blockIdx.x * blockDim.x + threadIdx.x;
    int stride = gridDim.x * blockDim.x;
    for (; i < n8; i += stride) {
        float4 e0 = emb[2 * i], e1 = emb[2 * i + 1];
        float4 z0 = zs[2 * i], z1 = zs[2 * i + 1];
        float g0 = e0.x * (2.f / (1.f + __expf(-z0.x)) - 1.f);
        float g1 = e0.y * (2.f / (1.f + __expf(-z0.y)) - 1.f);
        float g2 = e0.z * (2.f / (1.f + __expf(-z0.z)) - 1.f);
        float g3 = e0.w * (2.f / (1.f + __expf(-z0.w)) - 1.f);
        float g4 = e1.x * (2.f / (1.f + __expf(-z1.x)) - 1.f);
        float g5 = e1.y * (2.f / (1.f + __expf(-z1.y)) - 1.f);
        float g6 = e1.z * (2.f / (1.f + __expf(-z1.z)) - 1.f);
        float g7 = e1.w * (2.f / (1.f + __expf(-z1.w)) - 1.f);
        union { __half2 h[4]; float4 f; } u;
        u.h[0] = __floats2half2_rn(g0, g1);
        u.h[1] = __floats2half2_rn(g2, g3);
        u.h[2] = __floats2half2_rn(g4, g5);
        u.h[3] = __floats2half2_rn(g6, g7);
        gated_h[i] = u.f;
    }
}

// ---------------- pass B1: per-bin exclusive scan across blocks ----------------

__global__ void binscan_kernel(const int* __restrict__ ghist, int* __restrict__ gofs,
                               int* __restrict__ btot, int NBIN, int NBLK) {
    const int bin = blockIdx.x * 4 + (threadIdx.x >> 6);
    if (bin >= NBIN) return;
    const int lane = threadIdx.x & 63;
    const int* src = ghist + (size_t)bin * NBLK;
    int* dst = gofs + (size_t)bin * NBLK;
    int carry = 0;
    for (int k = 0; k < NBLK; k += 64) {
        int b = k + lane;
        int v = (b < NBLK) ? src[b] : 0;
        int x = v;
        #pragma unroll
        for (int off = 1; off < 64; off <<= 1) {
            int t = __shfl_up(x, off, 64);
            if (lane >= off) x += t;
        }
        if (b < NBLK) dst[b] = carry + x - v;
        carry += __shfl(x, 63, 64);
    }
    if (lane == 0) btot[bin] = carry;
}

// ---------------- pass B2: single-block scan over bins ----------------

__global__ void scan_kernel(const int* __restrict__ counts,
                            int* __restrict__ starts, int n) {
    __shared__ int wsum[16];
    __shared__ int wpre[16];
    __shared__ int total_s;
    __shared__ int carry_s;
    const int tid = threadIdx.x;
    const int lane = tid & 63;
    const int wid = tid >> 6;
    if (tid == 0) carry_s = 0;
    __syncthreads();
    for (int base = 0; base < n; base += 4096) {
        int i0 = base + tid * 4;
        int4 v = make_int4(0, 0, 0, 0);
        if (i0 + 0 < n) v.x = counts[i0 + 0];
        if (i0 + 1 < n) v.y = counts[i0 + 1];
        if (i0 + 2 < n) v.z = counts[i0 + 2];
        if (i0 + 3 < n) v.w = counts[i0 + 3];
        int s0 = v.x, s1 = s0 + v.y, s2 = s1 + v.z, s3 = s2 + v.w;
        int x = s3;
        #pragma unroll
        for (int off = 1; off < 64; off <<= 1) {
            int t = __shfl_up(x, off, 64);
            if (lane >= off) x += t;
        }
        if (lane == 63) wsum[wid] = x;
        __syncthreads();
        if (tid < 16) {
            int s = wsum[tid];
            #pragma unroll
            for (int off = 1; off < 16; off <<= 1) {
                int t = __shfl_up(s, off, 64);
                if (tid >= off) s += t;
            }
            wpre[tid] = s - wsum[tid];
            if (tid == 15) total_s = s;
        }
        __syncthreads();
        int pre = carry_s + wpre[wid] + (x - s3);
        if (i0 + 0 < n) starts[i0 + 0] = pre;
        if (i0 + 1 < n) starts[i0 + 1] = pre + s0;
        if (i0 + 2 < n) starts[i0 + 2] = pre + s1;
        if (i0 + 3 < n) starts[i0 + 3] = pre + s2;
        __syncthreads();
        if (tid == 0) carry_s += total_s;
        __syncthreads();
    }
    if (tid == 0) starts[n] = carry_s;
}

// ---------------- pass C: counting-sort scatter into buckets (LDS cursors) ----

__global__ void scatter_sort_kernel(const int* __restrict__ row, const int* __restrict__ col,
                                    const float* __restrict__ val,
                                    const int* __restrict__ gofs, const int* __restrict__ bstart,
                                    int2* __restrict__ sorted, int E, int NBIN, int NBLK) {
    __shared__ int cur[MAXBIN];
    const int b = blockIdx.x;
    for (int i = threadIdx.x; i < NBIN; i += 256)
        cur[i] = bstart[i] + gofs[(size_t)i * NBLK + b];
    __syncthreads();
    const int base = b * CHUNK;
    #pragma unroll
    for (int it = 0; it < CHUNK / 256; ++it) {
        int e = base + it * 256 + threadIdx.x;
        if (e < E) {
            int r = row[e];
            int slot = atomicAdd(&cur[r >> RPB_SHIFT], 1);
            sorted[slot] = make_int2(col[e] | ((r & (RPB - 1)) << PACK_SHIFT),
                                     __float_as_int(val[e]));
        }
    }
}

// ---------------- pass D: within-bucket row sort -> full CSR + rowstart ------

__global__ void rowsort_kernel(const int2* __restrict__ sorted,
                               const int* __restrict__ bstart,
                               int2* __restrict__ csr,
                               int* __restrict__ rowstart, int N, int NBIN, int E) {
    __shared__ int cnt[RPB];
    __shared__ int cur[RPB];
    __shared__ int wsum[4];
    const int bin = blockIdx.x;
    const int tid = threadIdx.x;
    const int lane = tid & 63;
    const int wid = tid >> 6;
    for (int i = tid; i < RPB; i += 256) cnt[i] = 0;
    __syncthreads();
    const int beg = bstart[bin], end = bstart[bin + 1];
    for (int e = beg + tid; e < end; e += 256) {
        int rl = ((unsigned)sorted[e].x) >> PACK_SHIFT;
        atomicAdd(&cnt[rl], 1);
    }
    __syncthreads();
    int v = (tid < RPB) ? cnt[tid] : 0;
    int x = v;
    #pragma unroll
    for (int off = 1; off < 64; off <<= 1) {
        int t = __shfl_up(x, off, 64);
        if (lane >= off) x += t;
    }
    if (lane == 63) wsum[wid] = x;
    __syncthreads();
    int base = 0;
    #pragma unroll
    for (int w = 0; w < 4; ++w) if (w < wid) base += wsum[w];
    int excl = base + x - v;
    if (tid < RPB) {
        cur[tid] = beg + excl;
        int r = bin * RPB + tid;
        if (r < N) rowstart[r] = beg + excl;
    }
    if (tid == 0 && bin == 0) rowstart[N] = E;
    __syncthreads();
    for (int e = beg + tid; e < end; e += 256) {
        int2 cv = sorted[e];
        int rl = ((unsigned)cv.x) >> PACK_SHIFT;
        int slot = atomicAdd(&cur[rl], 1);
        csr[slot] = make_int2(cv.x & ((1 << PACK_SHIFT) - 1), cv.y);
    }
}

// ---------------- pass E: one wave per row, unroll-8 batched gather ----------

__global__ void gather_h_kernel(const int* __restrict__ starts,
                                const int2* __restrict__ csr,
                                const __half2* __restrict__ gated,
                                float* __restrict__ out, int N) {
    int gid = blockIdx.x * blockDim.x + threadIdx.x;
    int r = gid >> 6;
    if (r >= N) return;
    int lane = gid & 63;
    int beg = __builtin_amdgcn_readfirstlane(starts[r]);
    int end = __builtin_amdgcn_readfirstlane(starts[r + 1]);
    float2 acc = make_float2(0.f, 0.f);
    for (int base = beg; base < end; base += 8) {
        int m = end - base;                 // >= 1
        int2 cv[8];
        #pragma unroll
        for (int k = 0; k < 8; ++k)
            cv[k] = csr[base + (k < m ? k : m - 1)];   // clamped, uniform addr
        float2 g[8];
        #pragma unroll
        for (int k = 0; k < 8; ++k)
            g[k] = __half22float2(gated[(size_t)cv[k].x * 64 + lane]);
        #pragma unroll
        for (int k = 0; k < 8; ++k) {
            float v = (k < m) ? __int_as_float(cv[k].y) : 0.f;
            acc.x += v * g[k].x;
            acc.y += v * g[k].y;
        }
    }
    acc.x = acc.x > 0.f ? acc.x : LEAKY * acc.x;
    acc.y = acc.y > 0.f ? acc.y : LEAKY * acc.y;
    ((float2*)out)[(size_t)r * 64 + lane] = acc;
}

// ---------------- last-resort fallback (round-1, known-good, ws-free) --------

__global__ void zero4_kernel(float4* __restrict__ out, int n4) {
    int i = blockIdx.x * blockDim.x + threadIdx.x;
    int stride = gridDim.x * blockDim.x;
    float4 z = make_float4(0.f, 0.f, 0.f, 0.f);
    for (; i < n4; i += stride) out[i] = z;
}

__global__ void scatter_fused_kernel(const int* __restrict__ row,
                                     const int* __restrict__ col,
                                     const float* __restrict__ val,
                                     const float* __restrict__ emb,
                                     const float* __restrict__ zs,
                                     float* __restrict__ out, int E) {
    int gid = blockIdx.x * blockDim.x + threadIdx.x;
    int e = gid >> 5;
    if (e >= E) return;
    int lane = gid & 31;
    int r = row[e];
    int c = col[e];
    float v = val[e];
    const float4* ep = (const float4*)(emb + (size_t)c * DD);
    const float4* zp = (const float4*)(zs + (size_t)c * DD);
    float4 ev = ep[lane];
    float4 zv = zp[lane];
    float4 gv;
    gv.x = ev.x * (2.f / (1.f + __expf(-zv.x)) - 1.f);
    gv.y = ev.y * (2.f / (1.f + __expf(-zv.y)) - 1.f);
    gv.z = ev.z * (2.f / (1.f + __expf(-zv.z)) - 1.f);
    gv.w = ev.w * (2.f / (1.f + __expf(-zv.w)) - 1.f);
    float* o = out + (size_t)r * DD + lane * 4;
    atomicAdd(o + 0, v * gv.x);
    atomicAdd(o + 1, v * gv.y);
    atomicAdd(o + 2, v * gv.z);
    atomicAdd(o + 3, v * gv.w);
}

__global__ void leaky_kernel(float4* __restrict__ out, int n4) {
    int i = blockIdx.x * blockDim.x + threadIdx.x;
    int stride = gridDim.x * blockDim.x;
    for (; i < n4; i += stride) {
        float4 x = out[i];
        x.x = x.x > 0.f ? x.x : LEAKY * x.x;
        x.y = x.y > 0.f ? x.y : LEAKY * x.y;
        x.z = x.z > 0.f ? x.z : LEAKY * x.z;
        x.w = x.w > 0.f ? x.w : LEAKY * x.w;
        out[i] = x;
    }
}

// ---------------- launch ----------------

extern "C" void kernel_launch(void* const* d_in, const int* in_sizes, int n_in,
                              void* d_out, int out_size, void* d_ws, size_t ws_size,
                              hipStream_t stream) {
    const int* row_idx = (const int*)d_in[0];
    const int* col_idx = (const int*)d_in[1];
    const float* adj_vals = (const float*)d_in[2];
    const float* embeds = (const float*)d_in[3];
    const float* zishiying = (const float*)d_in[4];
    float* out = (float*)d_out;

    const int E = in_sizes[0];
    const int ND = in_sizes[3];        // N * 128
    const int N = ND / DD;
    const int n4 = ND / 4;
    const int n8 = ND / 8;
    const int NBIN = (N + RPB - 1) / RPB;
    const int NBLK = (E + CHUNK - 1) / CHUNK;

    // ws layout
    char* p = (char*)d_ws;
    __half2* gated = (__half2*)p;          p += (size_t)ND * 2;
    int* ghist = (int*)p;                  p += (size_t)NBIN * NBLK * 4;
    int* gofs = (int*)p;                   p += (size_t)NBIN * NBLK * 4;
    int* btot = (int*)p;                   p += (size_t)NBIN * 4;
    int* bstart = (int*)p;                 p += (size_t)(NBIN + 1) * 4;
    int* rowstart = (int*)p;               p += (size_t)(N + 1) * 4;
    p = (char*)(((uintptr_t)p + 15) & ~(uintptr_t)15);
    int2* sorted = (int2*)p;               p += (size_t)E * 8;
    int2* csr = (int2*)p;                  p += (size_t)E * 8;
    const size_t need = (size_t)(p - (char*)d_ws);

    const int gb8 = min((n8 + 255) / 256, 2048);

    const bool ok = (NBIN <= MAXBIN) && (NBLK <= MAXBLK) && (N <= (1 << PACK_SHIFT)) &&
                    (ws_size >= need);

    if (ok) {
        int fused_grid = max(NBLK, gb8);
        hipLaunchKernelGGL(gatehist_kernel, dim3(fused_grid), dim3(256), 0, stream,
                           (const float4*)embeds, (const float4*)zishiying,
                           (float4*)gated, n8, row_idx, ghist, E, NBIN, NBLK);
        hipLaunchKernelGGL(binscan_kernel, dim3((NBIN + 3) / 4), dim3(256), 0, stream,
                           ghist, gofs, btot, NBIN, NBLK);
        hipLaunchKernelGGL(scan_kernel, dim3(1), dim3(1024), 0, stream,
                           btot, bstart, NBIN);
        hipLaunchKernelGGL(scatter_sort_kernel, dim3(NBLK), dim3(256), 0, stream,
                           row_idx, col_idx, adj_vals, gofs, bstart, sorted, E, NBIN, NBLK);
        hipLaunchKernelGGL(rowsort_kernel, dim3(NBIN), dim3(256), 0, stream,
                           sorted, bstart, csr, rowstart, N, NBIN, E);
        long long total = (long long)N * 64;
        int blocks = (int)((total + 255) / 256);
        hipLaunchKernelGGL(gather_h_kernel, dim3(blocks), dim3(256), 0, stream,
                           rowstart, csr, gated, out, N);
        return;
    }

    // ---------- last-resort atomic path ----------
    const int gb = min((n4 + 255) / 256, 2048);
    hipLaunchKernelGGL(zero4_kernel, dim3(gb), dim3(256), 0, stream, (float4*)out, n4);
    {
        long long total = (long long)E * 32;
        int sblocks = (int)((total + 255) / 256);
        hipLaunchKernelGGL(scatter_fused_kernel, dim3(sblocks), dim3(256), 0, stream,
                           row_idx, col_idx, adj_vals, embeds, zishiying, out, E);
    }
    hipLaunchKernelGGL(leaky_kernel, dim3(gb), dim3(256), 0, stream, (float4*)out, n4);
}

// Round 10
// 136.395 us; speedup vs baseline: 8.5997x; 1.0564x over previous
//
#include <hip/hip_runtime.h>
#include <hip/hip_fp16.h>
#include <math.h>

#define DD 128
#define LEAKY 0.5f
#define RPB 128             // rows per bucket (power of 2)
#define RPB_SHIFT 7
#define MAXBIN 1024         // >= ceil(N/RPB); LDS hist/cursor = 4 KB
#define CHUNK 2048          // edges per partition block
#define MAXBLK 1024         // >= ceil(E/CHUNK)
#define PACK_SHIFT 20       // col in low 20 bits, row_local (7b) above

// ---------------- fused pass: gate (fp16) + per-block bucket histogram -------
// ghistT layout: [block][bin]  (coalesced writes here, coalesced reads in scatter)

__global__ void gatehist_kernel(const float4* __restrict__ emb,
                                const float4* __restrict__ zs,
                                float4* __restrict__ gated_h, int n8,
                                const int* __restrict__ row, int* __restrict__ ghistT,
                                int E, int NBIN, int NBLK) {
    __shared__ int hist[MAXBIN];
    const int b = blockIdx.x;
    if (b < NBLK) {
        for (int i = threadIdx.x; i < NBIN; i += 256) hist[i] = 0;
        __syncthreads();
        const int base = b * CHUNK;
        #pragma unroll
        for (int it = 0; it < CHUNK / 256; ++it) {
            int e = base + it * 256 + threadIdx.x;
            if (e < E) atomicAdd(&hist[row[e] >> RPB_SHIFT], 1);
        }
        __syncthreads();
        for (int i = threadIdx.x; i < NBIN; i += 256)
            ghistT[(size_t)b * NBIN + i] = hist[i];
    }
    // gate slice (grid-stride over all blocks)
    int i = blockIdx.x * blockDim.x + threadIdx.x;
    int stride = gridDim.x * blockDim.x;
    for (; i < n8; i += stride) {
        float4 e0 = emb[2 * i], e1 = emb[2 * i + 1];
        float4 z0 = zs[2 * i], z1 = zs[2 * i + 1];
        float g0 = e0.x * (2.f / (1.f + __expf(-z0.x)) - 1.f);
        float g1 = e0.y * (2.f / (1.f + __expf(-z0.y)) - 1.f);
        float g2 = e0.z * (2.f / (1.f + __expf(-z0.z)) - 1.f);
        float g3 = e0.w * (2.f / (1.f + __expf(-z0.w)) - 1.f);
        float g4 = e1.x * (2.f / (1.f + __expf(-z1.x)) - 1.f);
        float g5 = e1.y * (2.f / (1.f + __expf(-z1.y)) - 1.f);
        float g6 = e1.z * (2.f / (1.f + __expf(-z1.z)) - 1.f);
        float g7 = e1.w * (2.f / (1.f + __expf(-z1.w)) - 1.f);
        union { __half2 h[4]; float4 f; } u;
        u.h[0] = __floats2half2_rn(g0, g1);
        u.h[1] = __floats2half2_rn(g2, g3);
        u.h[2] = __floats2half2_rn(g4, g5);
        u.h[3] = __floats2half2_rn(g6, g7);
        gated_h[i] = u.f;
    }
}

// ---------------- pass B: per-bin exclusive scan across blocks (transposed) ---

__global__ void binscanT_kernel(const int* __restrict__ ghistT, int* __restrict__ gofsT,
                                int* __restrict__ btot, int NBIN, int NBLK) {
    const int bin = blockIdx.x * 4 + (threadIdx.x >> 6);
    if (bin >= NBIN) return;
    const int lane = threadIdx.x & 63;
    int carry = 0;
    for (int k = 0; k < NBLK; k += 64) {
        int b = k + lane;
        int v = (b < NBLK) ? ghistT[(size_t)b * NBIN + bin] : 0;
        int x = v;
        #pragma unroll
        for (int off = 1; off < 64; off <<= 1) {
            int t = __shfl_up(x, off, 64);
            if (lane >= off) x += t;
        }
        if (b < NBLK) gofsT[(size_t)b * NBIN + bin] = carry + x - v;
        carry += __shfl(x, 63, 64);
    }
    if (lane == 0) btot[bin] = carry;
}

// ---------------- pass C: counting-sort scatter; bstart computed in-block ----

__global__ void scatter_sortT_kernel(const int* __restrict__ row, const int* __restrict__ col,
                                     const float* __restrict__ val,
                                     const int* __restrict__ gofsT, const int* __restrict__ btot,
                                     int2* __restrict__ sorted, int E, int NBIN, int NBLK) {
    __shared__ int cur[MAXBIN];
    __shared__ int wsum[4];
    const int b = blockIdx.x;
    const int tid = threadIdx.x;
    const int lane = tid & 63;
    const int wid = tid >> 6;
    // load btot
    for (int i = tid; i < NBIN; i += 256) cur[i] = btot[i];
    __syncthreads();
    // in-place exclusive scan (4 per thread) + add this block's gofsT
    int i0 = tid * 4;
    int c0 = (i0 + 0 < NBIN) ? cur[i0 + 0] : 0;
    int c1 = (i0 + 1 < NBIN) ? cur[i0 + 1] : 0;
    int c2 = (i0 + 2 < NBIN) ? cur[i0 + 2] : 0;
    int c3 = (i0 + 3 < NBIN) ? cur[i0 + 3] : 0;
    int s0 = c0, s1 = s0 + c1, s2 = s1 + c2, s3 = s2 + c3;
    int x = s3;
    #pragma unroll
    for (int off = 1; off < 64; off <<= 1) {
        int t = __shfl_up(x, off, 64);
        if (lane >= off) x += t;
    }
    if (lane == 63) wsum[wid] = x;
    __syncthreads();
    int base = 0;
    #pragma unroll
    for (int w = 0; w < 4; ++w) if (w < wid) base += wsum[w];
    int excl = base + x - s3;
    const size_t gbase = (size_t)b * NBIN;
    if (i0 + 0 < NBIN) cur[i0 + 0] = excl + gofsT[gbase + i0 + 0];
    if (i0 + 1 < NBIN) cur[i0 + 1] = excl + s0 + gofsT[gbase + i0 + 1];
    if (i0 + 2 < NBIN) cur[i0 + 2] = excl + s1 + gofsT[gbase + i0 + 2];
    if (i0 + 3 < NBIN) cur[i0 + 3] = excl + s2 + gofsT[gbase + i0 + 3];
    __syncthreads();
    // scatter this block's edge chunk
    const int ebase = b * CHUNK;
    #pragma unroll
    for (int it = 0; it < CHUNK / 256; ++it) {
        int e = ebase + it * 256 + tid;
        if (e < E) {
            int r = row[e];
            int slot = atomicAdd(&cur[r >> RPB_SHIFT], 1);
            sorted[slot] = make_int2(col[e] | ((r & (RPB - 1)) << PACK_SHIFT),
                                     __float_as_int(val[e]));
        }
    }
}

// ---------------- pass D: within-bucket row sort; bstart computed in-block ---

__global__ void rowsortT_kernel(const int2* __restrict__ sorted,
                                const int* __restrict__ btot,
                                int2* __restrict__ csr,
                                int* __restrict__ rowstart, int N, int NBIN, int E) {
    __shared__ int bs[MAXBIN + 1];
    __shared__ int wsA[4];
    __shared__ int cnt[RPB];
    __shared__ int cur[RPB];
    __shared__ int wsB[4];
    const int bin = blockIdx.x;
    const int tid = threadIdx.x;
    const int lane = tid & 63;
    const int wid = tid >> 6;
    // bstart = excl scan of btot (redundant per block, cheap)
    for (int i = tid; i < NBIN; i += 256) bs[i] = btot[i];
    __syncthreads();
    {
        int i0 = tid * 4;
        int c0 = (i0 + 0 < NBIN) ? bs[i0 + 0] : 0;
        int c1 = (i0 + 1 < NBIN) ? bs[i0 + 1] : 0;
        int c2 = (i0 + 2 < NBIN) ? bs[i0 + 2] : 0;
        int c3 = (i0 + 3 < NBIN) ? bs[i0 + 3] : 0;
        int s0 = c0, s1 = s0 + c1, s2 = s1 + c2, s3 = s2 + c3;
        int x = s3;
        #pragma unroll
        for (int off = 1; off < 64; off <<= 1) {
            int t = __shfl_up(x, off, 64);
            if (lane >= off) x += t;
        }
        if (lane == 63) wsA[wid] = x;
        __syncthreads();
        int base = 0;
        #pragma unroll
        for (int w = 0; w < 4; ++w) if (w < wid) base += wsA[w];
        int excl = base + x - s3;
        if (i0 + 0 < NBIN) bs[i0 + 0] = excl;
        if (i0 + 1 < NBIN) bs[i0 + 1] = excl + s0;
        if (i0 + 2 < NBIN) bs[i0 + 2] = excl + s1;
        if (i0 + 3 < NBIN) bs[i0 + 3] = excl + s2;
        if (tid == 0) bs[NBIN] = E;
    }
    for (int i = tid; i < RPB; i += 256) cnt[i] = 0;
    __syncthreads();
    const int beg = bs[bin], end = bs[bin + 1];
    for (int e = beg + tid; e < end; e += 256) {
        int rl = ((unsigned)sorted[e].x) >> PACK_SHIFT;
        atomicAdd(&cnt[rl], 1);
    }
    __syncthreads();
    int v = (tid < RPB) ? cnt[tid] : 0;
    int x = v;
    #pragma unroll
    for (int off = 1; off < 64; off <<= 1) {
        int t = __shfl_up(x, off, 64);
        if (lane >= off) x += t;
    }
    if (lane == 63) wsB[wid] = x;
    __syncthreads();
    int base = 0;
    #pragma unroll
    for (int w = 0; w < 4; ++w) if (w < wid) base += wsB[w];
    int excl = base + x - v;
    if (tid < RPB) {
        cur[tid] = beg + excl;
        int r = bin * RPB + tid;
        if (r < N) rowstart[r] = beg + excl;
    }
    if (tid == 0 && bin == 0) rowstart[N] = E;
    __syncthreads();
    for (int e = beg + tid; e < end; e += 256) {
        int2 cv = sorted[e];
        int rl = ((unsigned)cv.x) >> PACK_SHIFT;
        int slot = atomicAdd(&cur[rl], 1);
        csr[slot] = make_int2(cv.x & ((1 << PACK_SHIFT) - 1), cv.y);
    }
}

// ---------------- pass E: one wave per row, unroll-4 gather (R8 proven) ------

__global__ void gather_h_kernel(const int* __restrict__ starts,
                                const int2* __restrict__ csr,
                                const __half2* __restrict__ gated,
                                float* __restrict__ out, int N) {
    int gid = blockIdx.x * blockDim.x + threadIdx.x;
    int r = gid >> 6;
    if (r >= N) return;
    int lane = gid & 63;
    int beg = __builtin_amdgcn_readfirstlane(starts[r]);
    int end = __builtin_amdgcn_readfirstlane(starts[r + 1]);
    float2 acc = make_float2(0.f, 0.f);
    int j = beg;
    for (; j + 3 < end; j += 4) {
        int2 cv0 = csr[j];
        int2 cv1 = csr[j + 1];
        int2 cv2 = csr[j + 2];
        int2 cv3 = csr[j + 3];
        float2 g0 = __half22float2(gated[(size_t)cv0.x * 64 + lane]);
        float2 g1 = __half22float2(gated[(size_t)cv1.x * 64 + lane]);
        float2 g2 = __half22float2(gated[(size_t)cv2.x * 64 + lane]);
        float2 g3 = __half22float2(gated[(size_t)cv3.x * 64 + lane]);
        float v0 = __int_as_float(cv0.y);
        float v1 = __int_as_float(cv1.y);
        float v2 = __int_as_float(cv2.y);
        float v3 = __int_as_float(cv3.y);
        acc.x += v0 * g0.x; acc.y += v0 * g0.y;
        acc.x += v1 * g1.x; acc.y += v1 * g1.y;
        acc.x += v2 * g2.x; acc.y += v2 * g2.y;
        acc.x += v3 * g3.x; acc.y += v3 * g3.y;
    }
    for (; j < end; ++j) {
        int2 cv = csr[j];
        float2 g = __half22float2(gated[(size_t)cv.x * 64 + lane]);
        float v = __int_as_float(cv.y);
        acc.x += v * g.x; acc.y += v * g.y;
    }
    acc.x = acc.x > 0.f ? acc.x : LEAKY * acc.x;
    acc.y = acc.y > 0.f ? acc.y : LEAKY * acc.y;
    ((float2*)out)[(size_t)r * 64 + lane] = acc;
}

// ---------------- last-resort fallback (round-1, known-good, ws-free) --------

__global__ void zero4_kernel(float4* __restrict__ out, int n4) {
    int i = blockIdx.x * blockDim.x + threadIdx.x;
    int stride = gridDim.x * blockDim.x;
    float4 z = make_float4(0.f, 0.f, 0.f, 0.f);
    for (; i < n4; i += stride) out[i] = z;
}

__global__ void scatter_fused_kernel(const int* __restrict__ row,
                                     const int* __restrict__ col,
                                     const float* __restrict__ val,
                                     const float* __restrict__ emb,
                                     const float* __restrict__ zs,
                                     float* __restrict__ out, int E) {
    int gid = blockIdx.x * blockDim.x + threadIdx.x;
    int e = gid >> 5;
    if (e >= E) return;
    int lane = gid & 31;
    int r = row[e];
    int c = col[e];
    float v = val[e];
    const float4* ep = (const float4*)(emb + (size_t)c * DD);
    const float4* zp = (const float4*)(zs + (size_t)c * DD);
    float4 ev = ep[lane];
    float4 zv = zp[lane];
    float4 gv;
    gv.x = ev.x * (2.f / (1.f + __expf(-zv.x)) - 1.f);
    gv.y = ev.y * (2.f / (1.f + __expf(-zv.y)) - 1.f);
    gv.z = ev.z * (2.f / (1.f + __expf(-zv.z)) - 1.f);
    gv.w = ev.w * (2.f / (1.f + __expf(-zv.w)) - 1.f);
    float* o = out + (size_t)r * DD + lane * 4;
    atomicAdd(o + 0, v * gv.x);
    atomicAdd(o + 1, v * gv.y);
    atomicAdd(o + 2, v * gv.z);
    atomicAdd(o + 3, v * gv.w);
}

__global__ void leaky_kernel(float4* __restrict__ out, int n4) {
    int i = blockIdx.x * blockDim.x + threadIdx.x;
    int stride = gridDim.x * blockDim.x;
    for (; i < n4; i += stride) {
        float4 x = out[i];
        x.x = x.x > 0.f ? x.x : LEAKY * x.x;
        x.y = x.y > 0.f ? x.y : LEAKY * x.y;
        x.z = x.z > 0.f ? x.z : LEAKY * x.z;
        x.w = x.w > 0.f ? x.w : LEAKY * x.w;
        out[i] = x;
    }
}

// ---------------- launch ----------------

extern "C" void kernel_launch(void* const* d_in, const int* in_sizes, int n_in,
                              void* d_out, int out_size, void* d_ws, size_t ws_size,
                              hipStream_t stream) {
    const int* row_idx = (const int*)d_in[0];
    const int* col_idx = (const int*)d_in[1];
    const float* adj_vals = (const float*)d_in[2];
    const float* embeds = (const float*)d_in[3];
    const float* zishiying = (const float*)d_in[4];
    float* out = (float*)d_out;

    const int E = in_sizes[0];
    const int ND = in_sizes[3];        // N * 128
    const int N = ND / DD;
    const int n4 = ND / 4;
    const int n8 = ND / 8;
    const int NBIN = (N + RPB - 1) / RPB;
    const int NBLK = (E + CHUNK - 1) / CHUNK;

    // ws layout
    char* p = (char*)d_ws;
    __half2* gated = (__half2*)p;          p += (size_t)ND * 2;
    int* ghistT = (int*)p;                 p += (size_t)NBIN * NBLK * 4;
    int* gofsT = (int*)p;                  p += (size_t)NBIN * NBLK * 4;
    int* btot = (int*)p;                   p += (size_t)NBIN * 4;
    int* rowstart = (int*)p;               p += (size_t)(N + 1) * 4;
    p = (char*)(((uintptr_t)p + 15) & ~(uintptr_t)15);
    int2* sorted = (int2*)p;               p += (size_t)E * 8;
    int2* csr = (int2*)p;                  p += (size_t)E * 8;
    const size_t need = (size_t)(p - (char*)d_ws);

    const int gb8 = min((n8 + 255) / 256, 2048);

    const bool ok = (NBIN <= MAXBIN) && (NBLK <= MAXBLK) && (N <= (1 << PACK_SHIFT)) &&
                    (ws_size >= need);

    if (ok) {
        int fused_grid = max(NBLK, gb8);
        hipLaunchKernelGGL(gatehist_kernel, dim3(fused_grid), dim3(256), 0, stream,
                           (const float4*)embeds, (const float4*)zishiying,
                           (float4*)gated, n8, row_idx, ghistT, E, NBIN, NBLK);
        hipLaunchKernelGGL(binscanT_kernel, dim3((NBIN + 3) / 4), dim3(256), 0, stream,
                           ghistT, gofsT, btot, NBIN, NBLK);
        hipLaunchKernelGGL(scatter_sortT_kernel, dim3(NBLK), dim3(256), 0, stream,
                           row_idx, col_idx, adj_vals, gofsT, btot, sorted, E, NBIN, NBLK);
        hipLaunchKernelGGL(rowsortT_kernel, dim3(NBIN), dim3(256), 0, stream,
                           sorted, btot, csr, rowstart, N, NBIN, E);
        long long total = (long long)N * 64;
        int blocks = (int)((total + 255) / 256);
        hipLaunchKernelGGL(gather_h_kernel, dim3(blocks), dim3(256), 0, stream,
                           rowstart, csr, gated, out, N);
        return;
    }

    // ---------- last-resort atomic path ----------
    const int gb = min((n4 + 255) / 256, 2048);
    hipLaunchKernelGGL(zero4_kernel, dim3(gb), dim3(256), 0, stream, (float4*)out, n4);
    {
        long long total = (long long)E * 32;
        int sblocks = (int)((total + 255) / 256);
        hipLaunchKernelGGL(scatter_fused_kernel, dim3(sblocks), dim3(256), 0, stream,
                           row_idx, col_idx, adj_vals, embeds, zishiying, out, E);
    }
    hipLaunchKernelGGL(leaky_kernel, dim3(gb), dim3(256), 0, stream, (float4*)out, n4);
}